// Round 4
// baseline (140.627 us; speedup 1.0000x reference)
//
#include <hip/hip_runtime.h>

#define NB 64
#define NC 256
#define NF 262144          // C*H*W per batch
#define NROWS 524288       // B*C*H  (snr_map rows)

// ---------------------------------------------------------------------------
// Threefry-2x32 (JAX), 20 rounds.
// ---------------------------------------------------------------------------
struct U2 { unsigned a, b; };

__host__ __device__ constexpr unsigned rotl32(unsigned x, int d) {
  return (x << d) | (x >> (32 - d));
}

__host__ __device__ constexpr U2 tf2x32(unsigned k0, unsigned k1,
                                        unsigned x0, unsigned x1) {
  const unsigned ks0 = k0, ks1 = k1, ks2 = k0 ^ k1 ^ 0x1BD11BDAu;
  x0 += ks0; x1 += ks1;
  x0 += x1; x1 = rotl32(x1, 13); x1 ^= x0;
  x0 += x1; x1 = rotl32(x1, 15); x1 ^= x0;
  x0 += x1; x1 = rotl32(x1, 26); x1 ^= x0;
  x0 += x1; x1 = rotl32(x1, 6);  x1 ^= x0;
  x0 += ks1; x1 += ks2 + 1u;
  x0 += x1; x1 = rotl32(x1, 17); x1 ^= x0;
  x0 += x1; x1 = rotl32(x1, 29); x1 ^= x0;
  x0 += x1; x1 = rotl32(x1, 16); x1 ^= x0;
  x0 += x1; x1 = rotl32(x1, 24); x1 ^= x0;
  x0 += ks2; x1 += ks0 + 2u;
  x0 += x1; x1 = rotl32(x1, 13); x1 ^= x0;
  x0 += x1; x1 = rotl32(x1, 15); x1 ^= x0;
  x0 += x1; x1 = rotl32(x1, 26); x1 ^= x0;
  x0 += x1; x1 = rotl32(x1, 6);  x1 ^= x0;
  x0 += ks0; x1 += ks1 + 3u;
  x0 += x1; x1 = rotl32(x1, 17); x1 ^= x0;
  x0 += x1; x1 = rotl32(x1, 29); x1 ^= x0;
  x0 += x1; x1 = rotl32(x1, 16); x1 ^= x0;
  x0 += x1; x1 = rotl32(x1, 24); x1 ^= x0;
  x0 += ks1; x1 += ks2 + 4u;
  x0 += x1; x1 = rotl32(x1, 13); x1 ^= x0;
  x0 += x1; x1 = rotl32(x1, 15); x1 ^= x0;
  x0 += x1; x1 = rotl32(x1, 26); x1 ^= x0;
  x0 += x1; x1 = rotl32(x1, 6);  x1 ^= x0;
  x0 += ks2; x1 += ks0 + 5u;
  return U2{x0, x1};
}

// nk = split(key(42), 5); key(42) = (0, 42)
constexpr U2 NK0 = tf2x32(0u, 42u, 0u, 0u);
constexpr U2 NK1 = tf2x32(0u, 42u, 0u, 1u);
constexpr U2 NK2 = tf2x32(0u, 42u, 0u, 2u);
constexpr U2 NK3 = tf2x32(0u, 42u, 0u, 3u);
constexpr U2 NK4 = tf2x32(0u, 42u, 0u, 4u);
// kk = split(nk[4], 2)
constexpr U2 KK0 = tf2x32(NK4.a, NK4.b, 0u, 0u);
constexpr U2 KK1 = tf2x32(NK4.a, NK4.b, 0u, 1u);

// Device cipher: partitionable stream, out[m] = x0^x1 of block (0, m).
__device__ __forceinline__ unsigned rb32(unsigned k0, unsigned k1, unsigned m) {
  const unsigned ks2 = k0 ^ k1 ^ 0x1BD11BDAu;
  unsigned x0 = k0, x1 = m + k1;
#define QR(r) x0 += x1; x1 = __builtin_rotateleft32(x1, r); x1 ^= x0;
  QR(13) QR(15) QR(26) QR(6)
  x0 += k1;  x1 += ks2 + 1u;
  QR(17) QR(29) QR(16) QR(24)
  x0 += ks2; x1 += k0 + 2u;
  QR(13) QR(15) QR(26) QR(6)
  x0 += k0;  x1 += k1 + 3u;
  QR(17) QR(29) QR(16) QR(24)
  x0 += k1;  x1 += ks2 + 4u;
  QR(13) QR(15) QR(26) QR(6)
  x0 += ks2; x1 += k0 + 5u;
#undef QR
  return x0 ^ x1;
}

// ---------------------------------------------------------------------------
// normal draw scaled by K: K * erfinv(u) * sqrt(2)-folded coefficients.
// S=0: K=sqrt(2) (unit normal); S=1: K=sqrt(2)*sqrt(0.2) (pre-scaled by STD).
// t = 1 - v^2 kept EXACT via fma (cancellation region feeds 1/den-amplified
// tails); coefficient pre-scaling is a <=0.5ulp compile-time fold.
// fmax(v,lo) dropped: fl(2u+lo) ranges [lo, 1-2^-24], clamp can never fire.
// ---------------------------------------------------------------------------
template <int S>
__device__ __forceinline__ float normal_fast(unsigned bits) {
  constexpr float K = (S == 0) ? 1.41421356f : 1.41421356f * 0.44721359f;
  const float lo = __uint_as_float(0xBF7FFFFFu);  // nextafter(-1,0)
  float u = __uint_as_float((bits >> 9) | 0x3F800000u) - 1.0f;  // [0,1)
  float v = fmaf(u, 2.0f, lo);                     // [lo, 1)
  float t = fmaf(-v, v, 1.0f);                     // 1 - v^2 (exact-ish)
  float L = __builtin_amdgcn_logf(t);              // log2(t)
  float p;
  if (L > -7.2134752f) {                           // w = -ln2*L < 5
    float z = fmaf(L, -0.69314718f, -2.5f);
    p = K * 2.81022636e-08f;
    p = fmaf(p, z, K * 3.43273939e-07f);
    p = fmaf(p, z, K * -3.5233877e-06f);
    p = fmaf(p, z, K * -4.39150654e-06f);
    p = fmaf(p, z, K * 0.00021858087f);
    p = fmaf(p, z, K * -0.00125372503f);
    p = fmaf(p, z, K * -0.00417768164f);
    p = fmaf(p, z, K * 0.246640727f);
    p = fmaf(p, z, K * 1.50140941f);
  } else {
    float w = L * -0.69314718f;
    float z = __builtin_amdgcn_sqrtf(w) - 3.0f;
    p = K * -0.000200214257f;
    p = fmaf(p, z, K * 0.000100950558f);
    p = fmaf(p, z, K * 0.00134934322f);
    p = fmaf(p, z, K * -0.00367342844f);
    p = fmaf(p, z, K * 0.00573950773f);
    p = fmaf(p, z, K * -0.0076224613f);
    p = fmaf(p, z, K * 0.00943887047f);
    p = fmaf(p, z, K * 1.00167406f);
    p = fmaf(p, z, K * 2.83297682f);
  }
  return p * v;
}

// ---------------------------------------------------------------------------
// Kernel 1: fused prep. Blocks [0,4096): sem mean (1 wave per (b,c) row).
// Blocks [4096,6144): std2 rows (snr's VALU hides inside sem's HBM time).
// ---------------------------------------------------------------------------
__global__ __launch_bounds__(256) void prep_kernel(const float* __restrict__ x,
                                                   float* __restrict__ sem,
                                                   float* __restrict__ std2) {
  if (blockIdx.x < 4096) {
    int row = (blockIdx.x * 256 + threadIdx.x) >> 6;
    int lane = threadIdx.x & 63;
    const float* rp = x + (size_t)row * 1024;
    float acc = 0.0f;
#pragma unroll
    for (int i = 0; i < 4; ++i) {
      float4 v = *(const float4*)(rp + i * 256 + lane * 4);
      acc += v.x + v.y + v.z + v.w;
    }
#pragma unroll
    for (int off = 32; off > 0; off >>= 1) acc += __shfl_down(acc, off, 64);
    if (lane == 0) sem[row] = acc * (1.0f / 1024.0f);
  } else {
    // randint(kk0, (B,C,H,1), 0, 29), leading-2 bits layout.
    const unsigned j = (blockIdx.x - 4096u) * 256u + threadIdx.x;
    unsigned hb = rb32(KK0.a, KK0.b, j);
    unsigned lb = rb32(KK0.a, KK0.b, NROWS + j);
    unsigned snr = ((hb % 29u) * 16u + (lb % 29u)) % 29u;  // 2^32 % 29 = 16
    std2[j] = __builtin_amdgcn_sqrtf(
        2.0f * __builtin_amdgcn_exp2f((float)snr * -0.33219281f));
  }
}

// ---------------------------------------------------------------------------
// Kernel 2: per-batch head -> s[b,c] = weights * topk-mask.
// 96 row-jobs (16 base_w1 + 16 sem/cond_proj + 64 r_w1) across 4 waves,
// 64-lane butterfly reduction per row.
// ---------------------------------------------------------------------------
__global__ __launch_bounds__(256) void head_kernel(
    const float* __restrict__ sem_g, const float* __restrict__ channel_embed,
    const float* __restrict__ snr_w1, const float* __restrict__ snr_b1,
    const float* __restrict__ snr_w2, const float* __restrict__ snr_b2,
    const float* __restrict__ base_w1, const float* __restrict__ base_w2,
    const float* __restrict__ sem_proj, const float* __restrict__ cond_proj,
    const float* __restrict__ out_proj, const float* __restrict__ r_w1,
    const float* __restrict__ r_b1, const float* __restrict__ r_w2,
    const float* __restrict__ r_b2, const float* __restrict__ r_w3,
    const float* __restrict__ r_b3, float* __restrict__ s_out) {
  __shared__ float conc_s[288];  // [sem(256) | ch_vec(16) | sv(16)]
  __shared__ float sv1_s[16];
  __shared__ float hid_s[16], g1_s[16];
  __shared__ float r1_s[64], r2_s[64];
  __shared__ float w_s[256];
  __shared__ int k_s;
  const int b = blockIdx.x, t = threadIdx.x;
  const int wv = t >> 6, ln = t & 63;

  conc_s[t] = sem_g[b * 256 + t];
  if (t < 16) {
    const float s_in = (float)(10.0 / 28.0);
    sv1_s[t] = fmaxf(0.0f, s_in * snr_w1[t] + snr_b1[t]);
  }
  __syncthreads();
  if (t < 16) {
    float a = snr_b2[t];
    for (int f = 0; f < 16; ++f) a += sv1_s[f] * snr_w2[t * 16 + f];
    conc_s[272 + t] = fmaxf(0.0f, a);           // sv
    conc_s[256 + t] = channel_embed[32 + t];    // ch_vec (CH_IDX=2)
  }
  __syncthreads();

  for (int j = wv; j < 96; j += 4) {
    float acc = 0.0f;
    if (j < 16) {
#pragma unroll
      for (int k = 0; k < 4; ++k)
        acc += base_w1[j * 256 + ln + k * 64] * conc_s[ln + k * 64];
    } else if (j < 32) {
      int r = j - 16;
#pragma unroll
      for (int k = 0; k < 4; ++k)
        acc += sem_proj[r * 256 + ln + k * 64] * conc_s[ln + k * 64];
      if (ln < 32) acc += cond_proj[r * 32 + ln] * conc_s[256 + ln];
    } else {
      int r = j - 32;
#pragma unroll
      for (int k = 0; k < 4; ++k)
        acc += r_w1[r * 288 + ln + k * 64] * conc_s[ln + k * 64];
      if (ln < 32) acc += r_w1[r * 288 + 256 + ln] * conc_s[256 + ln];
    }
#pragma unroll
    for (int off = 32; off > 0; off >>= 1) acc += __shfl_xor(acc, off, 64);
    if (ln == 0) {
      if (j < 16) hid_s[j] = fmaxf(0.0f, acc);
      else if (j < 32) g1_s[j - 16] = fmaxf(0.0f, acc);
      else r1_s[j - 32] = fmaxf(0.0f, acc + r_b1[j - 32]);
    }
  }
  __syncthreads();

  if (t < 64) {
    float a = r_b2[t];
    for (int j = 0; j < 64; ++j) a += r1_s[j] * r_w2[t * 64 + j];
    r2_s[t] = fmaxf(0.0f, a);
  }
  {
    float a1 = 0.0f, a2 = 0.0f;
#pragma unroll
    for (int i = 0; i < 16; ++i) {
      a1 += hid_s[i] * base_w2[t * 16 + i];
      a2 += g1_s[i] * out_proj[t * 16 + i];
    }
    float base = 1.0f / (1.0f + expf(-a1));
    float gate = 1.0f / (1.0f + expf(-a2));
    w_s[t] = base * gate;
  }
  __syncthreads();
  if (t == 0) {
    float a = r_b3[0];
    for (int j = 0; j < 64; ++j) a += r2_s[j] * r_w3[j];
    float raw = 1.0f / (1.0f + expf(-a));
    float dyn = 0.3f + 0.7f * raw;
    float cr = 0.15f + 0.7f * dyn;
    cr = fminf(fmaxf(cr, 0.3f), 1.0f);
    int k = (int)rintf(cr * 256.0f);
    k_s = min(max(k, 1), 256);
  }
  __syncthreads();
  {
    float wc = w_s[t];
    int cnt = 0;
    for (int j = 0; j < 256; ++j) {
      float wj = w_s[j];
      cnt += (wj > wc) || (wj == wc && j < t);
    }
    s_out[b * 256 + t] = (cnt < k_s) ? wc : 0.0f;
  }
}

// ---------------------------------------------------------------------------
// Kernel 3: channel sim + noise. One thread per 8 floats (= 4 complex pairs).
// ---------------------------------------------------------------------------
__global__ __launch_bounds__(256) void sim_kernel(const float* __restrict__ x,
                                                  const float* __restrict__ s,
                                                  const float* __restrict__ std2v,
                                                  float* __restrict__ out) {
  const unsigned tid = blockIdx.x * 256u + threadIdx.x;   // 0 .. 2097151
  const unsigned q0 = tid * 8u;

  const float4 xa = *(const float4*)(x + q0);
  const float4 xb = *(const float4*)(x + q0 + 4);
  const float sc = s[q0 >> 10];
  const float std2 = std2v[q0 >> 5];

  // 24 independent cipher chains: 16 for h/n (pairs), 8 for n2.
  const unsigned m0 = tid * 4u;
  float hr[4], hi[4], nr[4], ni[4], n2[8];
#pragma unroll
  for (int i = 0; i < 4; ++i)
    hr[i] = normal_fast<0>(rb32(NK0.a, NK0.b, m0 + i));
#pragma unroll
  for (int i = 0; i < 4; ++i)
    hi[i] = normal_fast<0>(rb32(NK1.a, NK1.b, m0 + i));
#pragma unroll
  for (int i = 0; i < 4; ++i)
    nr[i] = normal_fast<1>(rb32(NK2.a, NK2.b, m0 + i));  // pre-scaled by STD
#pragma unroll
  for (int i = 0; i < 4; ++i)
    ni[i] = normal_fast<1>(rb32(NK3.a, NK3.b, m0 + i));
#pragma unroll
  for (int i = 0; i < 8; ++i)
    n2[i] = normal_fast<0>(rb32(KK1.a, KK1.b, q0 + i));

  // out = x*sc + (h* . n)/|h|^2 + std2*n2
  float xs[8] = {xa.x * sc, xa.y * sc, xa.z * sc, xa.w * sc,
                 xb.x * sc, xb.y * sc, xb.z * sc, xb.w * sc};
  float o[8];
#pragma unroll
  for (int i = 0; i < 4; ++i) {
    const float den = fmaf(hr[i], hr[i], hi[i] * hi[i]);
    const float rc = __builtin_amdgcn_rcpf(den);
    o[2 * i] = fmaf(fmaf(hr[i], nr[i], hi[i] * ni[i]), rc, xs[2 * i]);
    o[2 * i + 1] =
        fmaf(fmaf(hr[i], ni[i], -(hi[i] * nr[i])), rc, xs[2 * i + 1]);
  }
  float4 oa, ob;
  oa.x = fmaf(std2, n2[0], o[0]);
  oa.y = fmaf(std2, n2[1], o[1]);
  oa.z = fmaf(std2, n2[2], o[2]);
  oa.w = fmaf(std2, n2[3], o[3]);
  ob.x = fmaf(std2, n2[4], o[4]);
  ob.y = fmaf(std2, n2[5], o[5]);
  ob.z = fmaf(std2, n2[6], o[6]);
  ob.w = fmaf(std2, n2[7], o[7]);
  *(float4*)(out + q0) = oa;
  *(float4*)(out + q0 + 4) = ob;
}

// ---------------------------------------------------------------------------
extern "C" void kernel_launch(void* const* d_in, const int* in_sizes, int n_in,
                              void* d_out, int out_size, void* d_ws,
                              size_t ws_size, hipStream_t stream) {
  const float* x = (const float*)d_in[0];
  const float* channel_embed = (const float*)d_in[1];
  const float* snr_w1 = (const float*)d_in[2];
  const float* snr_b1 = (const float*)d_in[3];
  const float* snr_w2 = (const float*)d_in[4];
  const float* snr_b2 = (const float*)d_in[5];
  const float* base_w1 = (const float*)d_in[6];
  const float* base_w2 = (const float*)d_in[7];
  const float* sem_proj = (const float*)d_in[8];
  const float* cond_proj = (const float*)d_in[9];
  const float* out_proj = (const float*)d_in[10];
  const float* r_w1 = (const float*)d_in[11];
  const float* r_b1 = (const float*)d_in[12];
  const float* r_w2 = (const float*)d_in[13];
  const float* r_b2 = (const float*)d_in[14];
  const float* r_w3 = (const float*)d_in[15];
  const float* r_b3 = (const float*)d_in[16];

  float* std2 = (float*)d_ws;             // 524288 floats (2 MB)
  float* sem = std2 + NROWS;              // 16384 floats
  float* s = sem + NB * NC;               // 16384 floats

  prep_kernel<<<4096 + NROWS / 256, 256, 0, stream>>>(x, sem, std2);
  head_kernel<<<NB, 256, 0, stream>>>(sem, channel_embed, snr_w1, snr_b1,
                                      snr_w2, snr_b2, base_w1, base_w2,
                                      sem_proj, cond_proj, out_proj, r_w1,
                                      r_b1, r_w2, r_b2, r_w3, r_b3, s);
  sim_kernel<<<NB * NF / 8 / 256, 256, 0, stream>>>(x, s, std2, (float*)d_out);
}

// Round 5
// 128.261 us; speedup vs baseline: 1.0964x; 1.0964x over previous
//
#include <hip/hip_runtime.h>
#include <hip/hip_fp16.h>

#define NB 64
#define NC 256
#define NF 262144          // C*H*W per batch
#define NROWS 524288       // B*C*H  (snr_map rows)

// ---------------------------------------------------------------------------
// Threefry-2x32 (JAX), 20 rounds.
// ---------------------------------------------------------------------------
struct U2 { unsigned a, b; };

__host__ __device__ constexpr unsigned rotl32(unsigned x, int d) {
  return (x << d) | (x >> (32 - d));
}

__host__ __device__ constexpr U2 tf2x32(unsigned k0, unsigned k1,
                                        unsigned x0, unsigned x1) {
  const unsigned ks0 = k0, ks1 = k1, ks2 = k0 ^ k1 ^ 0x1BD11BDAu;
  x0 += ks0; x1 += ks1;
  x0 += x1; x1 = rotl32(x1, 13); x1 ^= x0;
  x0 += x1; x1 = rotl32(x1, 15); x1 ^= x0;
  x0 += x1; x1 = rotl32(x1, 26); x1 ^= x0;
  x0 += x1; x1 = rotl32(x1, 6);  x1 ^= x0;
  x0 += ks1; x1 += ks2 + 1u;
  x0 += x1; x1 = rotl32(x1, 17); x1 ^= x0;
  x0 += x1; x1 = rotl32(x1, 29); x1 ^= x0;
  x0 += x1; x1 = rotl32(x1, 16); x1 ^= x0;
  x0 += x1; x1 = rotl32(x1, 24); x1 ^= x0;
  x0 += ks2; x1 += ks0 + 2u;
  x0 += x1; x1 = rotl32(x1, 13); x1 ^= x0;
  x0 += x1; x1 = rotl32(x1, 15); x1 ^= x0;
  x0 += x1; x1 = rotl32(x1, 26); x1 ^= x0;
  x0 += x1; x1 = rotl32(x1, 6);  x1 ^= x0;
  x0 += ks0; x1 += ks1 + 3u;
  x0 += x1; x1 = rotl32(x1, 17); x1 ^= x0;
  x0 += x1; x1 = rotl32(x1, 29); x1 ^= x0;
  x0 += x1; x1 = rotl32(x1, 16); x1 ^= x0;
  x0 += x1; x1 = rotl32(x1, 24); x1 ^= x0;
  x0 += ks1; x1 += ks2 + 4u;
  x0 += x1; x1 = rotl32(x1, 13); x1 ^= x0;
  x0 += x1; x1 = rotl32(x1, 15); x1 ^= x0;
  x0 += x1; x1 = rotl32(x1, 26); x1 ^= x0;
  x0 += x1; x1 = rotl32(x1, 6);  x1 ^= x0;
  x0 += ks2; x1 += ks0 + 5u;
  return U2{x0, x1};
}

// nk = split(key(42), 5); key(42) = (0, 42)
constexpr U2 NK0 = tf2x32(0u, 42u, 0u, 0u);
constexpr U2 NK1 = tf2x32(0u, 42u, 0u, 1u);
constexpr U2 NK2 = tf2x32(0u, 42u, 0u, 2u);
constexpr U2 NK3 = tf2x32(0u, 42u, 0u, 3u);
constexpr U2 NK4 = tf2x32(0u, 42u, 0u, 4u);
// kk = split(nk[4], 2)
constexpr U2 KK0 = tf2x32(NK4.a, NK4.b, 0u, 0u);
constexpr U2 KK1 = tf2x32(NK4.a, NK4.b, 0u, 1u);

// Device cipher: partitionable stream, out[m] = x0^x1 of block (0, m).
__device__ __forceinline__ unsigned rb32(unsigned k0, unsigned k1, unsigned m) {
  const unsigned ks2 = k0 ^ k1 ^ 0x1BD11BDAu;
  unsigned x0 = k0, x1 = m + k1;
#define QR(r) x0 += x1; x1 = __builtin_rotateleft32(x1, r); x1 ^= x0;
  QR(13) QR(15) QR(26) QR(6)
  x0 += k1;  x1 += ks2 + 1u;
  QR(17) QR(29) QR(16) QR(24)
  x0 += ks2; x1 += k0 + 2u;
  QR(13) QR(15) QR(26) QR(6)
  x0 += k0;  x1 += k1 + 3u;
  QR(17) QR(29) QR(16) QR(24)
  x0 += k1;  x1 += ks2 + 4u;
  QR(13) QR(15) QR(26) QR(6)
  x0 += ks2; x1 += k0 + 5u;
#undef QR
  return x0 ^ x1;
}

// ---------------------------------------------------------------------------
// normal draw scaled by K (coefficients pre-folded at compile time).
// S=0: K=sqrt(2); S=1: K=sqrt(2)*sqrt(0.2).
// ---------------------------------------------------------------------------
template <int S>
__device__ __forceinline__ float normal_fast(unsigned bits) {
  constexpr float K = (S == 0) ? 1.41421356f : 1.41421356f * 0.44721359f;
  const float lo = __uint_as_float(0xBF7FFFFFu);  // nextafter(-1,0)
  float u = __uint_as_float((bits >> 9) | 0x3F800000u) - 1.0f;  // [0,1)
  float v = fmaf(u, 2.0f, lo);                     // [lo, 1)
  float t = fmaf(-v, v, 1.0f);                     // 1 - v^2 (exact via fma)
  float L = __builtin_amdgcn_logf(t);              // log2(t)
  float p;
  if (L > -7.2134752f) {                           // w = -ln2*L < 5
    float z = fmaf(L, -0.69314718f, -2.5f);
    p = K * 2.81022636e-08f;
    p = fmaf(p, z, K * 3.43273939e-07f);
    p = fmaf(p, z, K * -3.5233877e-06f);
    p = fmaf(p, z, K * -4.39150654e-06f);
    p = fmaf(p, z, K * 0.00021858087f);
    p = fmaf(p, z, K * -0.00125372503f);
    p = fmaf(p, z, K * -0.00417768164f);
    p = fmaf(p, z, K * 0.246640727f);
    p = fmaf(p, z, K * 1.50140941f);
  } else {
    float w = L * -0.69314718f;
    float z = __builtin_amdgcn_sqrtf(w) - 3.0f;
    p = K * -0.000200214257f;
    p = fmaf(p, z, K * 0.000100950558f);
    p = fmaf(p, z, K * 0.00134934322f);
    p = fmaf(p, z, K * -0.00367342844f);
    p = fmaf(p, z, K * 0.00573950773f);
    p = fmaf(p, z, K * -0.0076224613f);
    p = fmaf(p, z, K * 0.00943887047f);
    p = fmaf(p, z, K * 1.00167406f);
    p = fmaf(p, z, K * 2.83297682f);
  }
  return p * v;
}

__device__ __forceinline__ float std2_of_row(unsigned j) {
  // randint(kk0, (B,C,H,1), 0, 29), leading-2 bits layout.
  unsigned hb = rb32(KK0.a, KK0.b, j);
  unsigned lb = rb32(KK0.a, KK0.b, NROWS + j);
  unsigned snr = ((hb % 29u) * 16u + (lb % 29u)) % 29u;  // 2^32 % 29 = 16
  return __builtin_amdgcn_sqrtf(
      2.0f * __builtin_amdgcn_exp2f((float)snr * -0.33219281f));
}

// ---------------------------------------------------------------------------
// prep2 (main path): blocks [0,2048): one thread per (b,c,h) row -> writes
// noise2[j*32..+31] = std2(row) * n2 as f16 (VALU long-pole, starts first).
// Blocks [2048,6144): sem mean, 1 wave per (b,c) row (memory-bound; its HBM
// time hides under the n2 blocks' VALU).
// ---------------------------------------------------------------------------
__global__ __launch_bounds__(256) void prep2_kernel(const float* __restrict__ x,
                                                    float* __restrict__ sem,
                                                    __half* __restrict__ noise2) {
  if (blockIdx.x < 2048) {
    const unsigned j = blockIdx.x * 256u + threadIdx.x;  // row 0..524287
    const float std2 = std2_of_row(j);
    const unsigned q = j * 32u;
#pragma unroll
    for (int cc = 0; cc < 4; ++cc) {
      union { __half2 h2[4]; uint4 u; } pk;
#pragma unroll
      for (int e = 0; e < 4; ++e) {
        float a = std2 * normal_fast<0>(rb32(KK1.a, KK1.b, q + cc * 8u + 2 * e));
        float b = std2 * normal_fast<0>(rb32(KK1.a, KK1.b, q + cc * 8u + 2 * e + 1));
        pk.h2[e] = __floats2half2_rn(a, b);
      }
      *(uint4*)(noise2 + q + cc * 8u) = pk.u;
    }
  } else {
    int row = ((blockIdx.x - 2048) * 256 + threadIdx.x) >> 6;
    int lane = threadIdx.x & 63;
    const float* rp = x + (size_t)row * 1024;
    float acc = 0.0f;
#pragma unroll
    for (int i = 0; i < 4; ++i) {
      float4 v = *(const float4*)(rp + i * 256 + lane * 4);
      acc += v.x + v.y + v.z + v.w;
    }
#pragma unroll
    for (int off = 32; off > 0; off >>= 1) acc += __shfl_down(acc, off, 64);
    if (lane == 0) sem[row] = acc * (1.0f / 1024.0f);
  }
}

// Fallback prep (ws too small): std2 array instead of noise2.
__global__ __launch_bounds__(256) void prep_kernel(const float* __restrict__ x,
                                                   float* __restrict__ sem,
                                                   float* __restrict__ std2) {
  if (blockIdx.x < 2048) {
    const unsigned j = blockIdx.x * 256u + threadIdx.x;
    std2[j] = std2_of_row(j);
  } else {
    int row = ((blockIdx.x - 2048) * 256 + threadIdx.x) >> 6;
    int lane = threadIdx.x & 63;
    const float* rp = x + (size_t)row * 1024;
    float acc = 0.0f;
#pragma unroll
    for (int i = 0; i < 4; ++i) {
      float4 v = *(const float4*)(rp + i * 256 + lane * 4);
      acc += v.x + v.y + v.z + v.w;
    }
#pragma unroll
    for (int off = 32; off > 0; off >>= 1) acc += __shfl_down(acc, off, 64);
    if (lane == 0) sem[row] = acc * (1.0f / 1024.0f);
  }
}

// ---------------------------------------------------------------------------
// head: per-batch MLPs + topk mask (R3-proven serial-ILP version).
// ---------------------------------------------------------------------------
__global__ __launch_bounds__(256) void head_kernel(
    const float* __restrict__ sem_g, const float* __restrict__ channel_embed,
    const float* __restrict__ snr_w1, const float* __restrict__ snr_b1,
    const float* __restrict__ snr_w2, const float* __restrict__ snr_b2,
    const float* __restrict__ base_w1, const float* __restrict__ base_w2,
    const float* __restrict__ sem_proj, const float* __restrict__ cond_proj,
    const float* __restrict__ out_proj, const float* __restrict__ r_w1,
    const float* __restrict__ r_b1, const float* __restrict__ r_w2,
    const float* __restrict__ r_b2, const float* __restrict__ r_w3,
    const float* __restrict__ r_b3, float* __restrict__ s_out) {
  __shared__ float sem_s[256];
  __shared__ float sv1_s[16];
  __shared__ float cond_s[32];
  __shared__ float hid_s[16], g1_s[16];
  __shared__ float r1_s[64], r2_s[64];
  __shared__ float w_s[256];
  __shared__ int k_s;
  const int b = blockIdx.x, t = threadIdx.x;

  sem_s[t] = sem_g[b * 256 + t];
  if (t < 16) {
    const float s_in = (float)(10.0 / 28.0);
    sv1_s[t] = fmaxf(0.0f, s_in * snr_w1[t] + snr_b1[t]);
  }
  __syncthreads();
  if (t < 16) {
    float a = snr_b2[t];
    for (int f = 0; f < 16; ++f) a += sv1_s[f] * snr_w2[t * 16 + f];
    cond_s[16 + t] = fmaxf(0.0f, a);
    cond_s[t] = channel_embed[2 * 16 + t];  // CH_IDX=2
  }
  __syncthreads();
  if (t < 16) {
    float a1 = 0.0f, a2 = 0.0f;
    for (int c = 0; c < 256; ++c) {
      float sc = sem_s[c];
      a1 += sc * base_w1[t * 256 + c];
      a2 += sc * sem_proj[t * 256 + c];
    }
    for (int j = 0; j < 32; ++j) a2 += cond_s[j] * cond_proj[t * 32 + j];
    hid_s[t] = fmaxf(0.0f, a1);
    g1_s[t] = fmaxf(0.0f, a2);
  } else if (t < 80) {
    int i = t - 16;
    float a = r_b1[i];
    for (int c = 0; c < 256; ++c) a += sem_s[c] * r_w1[i * 288 + c];
    for (int j = 0; j < 32; ++j) a += cond_s[j] * r_w1[i * 288 + 256 + j];
    r1_s[i] = fmaxf(0.0f, a);
  }
  __syncthreads();
  if (t < 64) {
    float a = r_b2[t];
    for (int j = 0; j < 64; ++j) a += r1_s[j] * r_w2[t * 64 + j];
    r2_s[t] = fmaxf(0.0f, a);
  }
  {
    float a1 = 0.0f, a2 = 0.0f;
    for (int i = 0; i < 16; ++i) {
      a1 += hid_s[i] * base_w2[t * 16 + i];
      a2 += g1_s[i] * out_proj[t * 16 + i];
    }
    float base = 1.0f / (1.0f + expf(-a1));
    float gate = 1.0f / (1.0f + expf(-a2));
    w_s[t] = base * gate;
  }
  __syncthreads();
  if (t == 0) {
    float a = r_b3[0];
    for (int j = 0; j < 64; ++j) a += r2_s[j] * r_w3[j];
    float raw = 1.0f / (1.0f + expf(-a));
    float dyn = 0.3f + 0.7f * raw;
    float cr = 0.15f + 0.7f * dyn;
    cr = fminf(fmaxf(cr, 0.3f), 1.0f);
    int k = (int)rintf(cr * 256.0f);
    k_s = min(max(k, 1), 256);
  }
  __syncthreads();
  {
    float wc = w_s[t];
    int cnt = 0;
    for (int j = 0; j < 256; ++j) {
      float wj = w_s[j];
      cnt += (wj > wc) || (wj == wc && j < t);
    }
    s_out[b * 256 + t] = (cnt < k_s) ? wc : 0.0f;
  }
}

// ---------------------------------------------------------------------------
// sim2 (main): fading only; n2 noise read pre-materialized as f16.
// One thread per 8 floats (= 4 complex pairs).
// ---------------------------------------------------------------------------
__global__ __launch_bounds__(256) void sim2_kernel(
    const float* __restrict__ x, const float* __restrict__ s,
    const __half* __restrict__ noise2, float* __restrict__ out) {
  const unsigned tid = blockIdx.x * 256u + threadIdx.x;   // 0 .. 2097151
  const unsigned q0 = tid * 8u;

  const float4 xa = *(const float4*)(x + q0);
  const float4 xb = *(const float4*)(x + q0 + 4);
  const uint4 nbits = *(const uint4*)(noise2 + q0);
  const float sc = s[q0 >> 10];

  const unsigned m0 = tid * 4u;
  float hr[4], hi[4], nr[4], ni[4];
#pragma unroll
  for (int i = 0; i < 4; ++i)
    hr[i] = normal_fast<0>(rb32(NK0.a, NK0.b, m0 + i));
#pragma unroll
  for (int i = 0; i < 4; ++i)
    hi[i] = normal_fast<0>(rb32(NK1.a, NK1.b, m0 + i));
#pragma unroll
  for (int i = 0; i < 4; ++i)
    nr[i] = normal_fast<1>(rb32(NK2.a, NK2.b, m0 + i));
#pragma unroll
  for (int i = 0; i < 4; ++i)
    ni[i] = normal_fast<1>(rb32(NK3.a, NK3.b, m0 + i));

  union { uint4 u; __half2 h2[4]; } pk; pk.u = nbits;
  const float2 f01 = __half22float2(pk.h2[0]);
  const float2 f23 = __half22float2(pk.h2[1]);
  const float2 f45 = __half22float2(pk.h2[2]);
  const float2 f67 = __half22float2(pk.h2[3]);

  float xs[8] = {xa.x * sc, xa.y * sc, xa.z * sc, xa.w * sc,
                 xb.x * sc, xb.y * sc, xb.z * sc, xb.w * sc};
  float o[8];
#pragma unroll
  for (int i = 0; i < 4; ++i) {
    const float den = fmaf(hr[i], hr[i], hi[i] * hi[i]);
    const float rc = __builtin_amdgcn_rcpf(den);
    o[2 * i] = fmaf(fmaf(hr[i], nr[i], hi[i] * ni[i]), rc, xs[2 * i]);
    o[2 * i + 1] =
        fmaf(fmaf(hr[i], ni[i], -(hi[i] * nr[i])), rc, xs[2 * i + 1]);
  }
  float4 oa, ob;
  oa.x = o[0] + f01.x; oa.y = o[1] + f01.y;
  oa.z = o[2] + f23.x; oa.w = o[3] + f23.y;
  ob.x = o[4] + f45.x; ob.y = o[5] + f45.y;
  ob.z = o[6] + f67.x; ob.w = o[7] + f67.y;
  *(float4*)(out + q0) = oa;
  *(float4*)(out + q0 + 4) = ob;
}

// Fallback sim (ws too small): n2 generated inline (R4 behavior).
__global__ __launch_bounds__(256) void sim_kernel(const float* __restrict__ x,
                                                  const float* __restrict__ s,
                                                  const float* __restrict__ std2v,
                                                  float* __restrict__ out) {
  const unsigned tid = blockIdx.x * 256u + threadIdx.x;
  const unsigned q0 = tid * 8u;

  const float4 xa = *(const float4*)(x + q0);
  const float4 xb = *(const float4*)(x + q0 + 4);
  const float sc = s[q0 >> 10];
  const float std2 = std2v[q0 >> 5];

  const unsigned m0 = tid * 4u;
  float hr[4], hi[4], nr[4], ni[4], n2[8];
#pragma unroll
  for (int i = 0; i < 4; ++i)
    hr[i] = normal_fast<0>(rb32(NK0.a, NK0.b, m0 + i));
#pragma unroll
  for (int i = 0; i < 4; ++i)
    hi[i] = normal_fast<0>(rb32(NK1.a, NK1.b, m0 + i));
#pragma unroll
  for (int i = 0; i < 4; ++i)
    nr[i] = normal_fast<1>(rb32(NK2.a, NK2.b, m0 + i));
#pragma unroll
  for (int i = 0; i < 4; ++i)
    ni[i] = normal_fast<1>(rb32(NK3.a, NK3.b, m0 + i));
#pragma unroll
  for (int i = 0; i < 8; ++i)
    n2[i] = normal_fast<0>(rb32(KK1.a, KK1.b, q0 + i));

  float xs[8] = {xa.x * sc, xa.y * sc, xa.z * sc, xa.w * sc,
                 xb.x * sc, xb.y * sc, xb.z * sc, xb.w * sc};
  float o[8];
#pragma unroll
  for (int i = 0; i < 4; ++i) {
    const float den = fmaf(hr[i], hr[i], hi[i] * hi[i]);
    const float rc = __builtin_amdgcn_rcpf(den);
    o[2 * i] = fmaf(fmaf(hr[i], nr[i], hi[i] * ni[i]), rc, xs[2 * i]);
    o[2 * i + 1] =
        fmaf(fmaf(hr[i], ni[i], -(hi[i] * nr[i])), rc, xs[2 * i + 1]);
  }
  float4 oa, ob;
  oa.x = fmaf(std2, n2[0], o[0]);
  oa.y = fmaf(std2, n2[1], o[1]);
  oa.z = fmaf(std2, n2[2], o[2]);
  oa.w = fmaf(std2, n2[3], o[3]);
  ob.x = fmaf(std2, n2[4], o[4]);
  ob.y = fmaf(std2, n2[5], o[5]);
  ob.z = fmaf(std2, n2[6], o[6]);
  ob.w = fmaf(std2, n2[7], o[7]);
  *(float4*)(out + q0) = oa;
  *(float4*)(out + q0 + 4) = ob;
}

// ---------------------------------------------------------------------------
extern "C" void kernel_launch(void* const* d_in, const int* in_sizes, int n_in,
                              void* d_out, int out_size, void* d_ws,
                              size_t ws_size, hipStream_t stream) {
  const float* x = (const float*)d_in[0];
  const float* channel_embed = (const float*)d_in[1];
  const float* snr_w1 = (const float*)d_in[2];
  const float* snr_b1 = (const float*)d_in[3];
  const float* snr_w2 = (const float*)d_in[4];
  const float* snr_b2 = (const float*)d_in[5];
  const float* base_w1 = (const float*)d_in[6];
  const float* base_w2 = (const float*)d_in[7];
  const float* sem_proj = (const float*)d_in[8];
  const float* cond_proj = (const float*)d_in[9];
  const float* out_proj = (const float*)d_in[10];
  const float* r_w1 = (const float*)d_in[11];
  const float* r_b1 = (const float*)d_in[12];
  const float* r_w2 = (const float*)d_in[13];
  const float* r_b2 = (const float*)d_in[14];
  const float* r_w3 = (const float*)d_in[15];
  const float* r_b3 = (const float*)d_in[16];

  const size_t need = (size_t)NB * NF * sizeof(__half) + 2u * 16384u * 4u;
  if (ws_size >= need) {
    __half* noise2 = (__half*)d_ws;                       // 33.55 MB
    float* sem = (float*)((char*)d_ws + (size_t)NB * NF * sizeof(__half));
    float* s = sem + NB * NC;
    prep2_kernel<<<6144, 256, 0, stream>>>(x, sem, noise2);
    head_kernel<<<NB, 256, 0, stream>>>(sem, channel_embed, snr_w1, snr_b1,
                                        snr_w2, snr_b2, base_w1, base_w2,
                                        sem_proj, cond_proj, out_proj, r_w1,
                                        r_b1, r_w2, r_b2, r_w3, r_b3, s);
    sim2_kernel<<<NB * NF / 8 / 256, 256, 0, stream>>>(x, s, noise2,
                                                       (float*)d_out);
  } else {
    float* std2 = (float*)d_ws;                           // 2 MB
    float* sem = std2 + NROWS;
    float* s = sem + NB * NC;
    prep_kernel<<<6144, 256, 0, stream>>>(x, sem, std2);
    head_kernel<<<NB, 256, 0, stream>>>(sem, channel_embed, snr_w1, snr_b1,
                                        snr_w2, snr_b2, base_w1, base_w2,
                                        sem_proj, cond_proj, out_proj, r_w1,
                                        r_b1, r_w2, r_b2, r_w3, r_b3, s);
    sim_kernel<<<NB * NF / 8 / 256, 256, 0, stream>>>(x, s, std2,
                                                      (float*)d_out);
  }
}